// Round 14
// baseline (213.734 us; speedup 1.0000x reference)
//
#include <hip/hip_runtime.h>
#include <hip/hip_bf16.h>

// ---------------------------------------------------------------------------
// RRN, MFMA version, parallel scan-binned, bf16-resident e.
//   iter: e = l2norm(tanh([e;mem] @ Wc + bc))            (K=192 GEMM, MFMA)
//         per triple (unique rows): out = tanh([e_s;e_o] @ Wr[l] + br[l])
//         e[s]=l2norm(out[:128]); e[o]=l2norm(out[128:])  (layer-binned MFMA)
// subj ∪ obj are distinct rows -> in-place update race-free.
// k_class_p: global_load_lds double-buffered pipeline (payload-free staging:
//   16KB tile in flight per block -> read-latency no longer caps BW).
//   Pre-swizzled global source + linear LDS dest + XOR-swizzled reads
//   (2-way bank aliasing = free). emb->bf16 conversion moved into k_prep so
//   both class iters read bf16 (raw-copy compatible with gload_lds).
// k_rel: unchanged (R13). Old k_class kept as fallback for tiny ws.
// ---------------------------------------------------------------------------

#define NROWS 200000
#define DD    128
#define KK    64
#define TT    50000
#define LL    8
#define BT    64
#define PADT  50560            // 64*790 >= 50000 + 8*63
#define NPASS 3125             // NROWS/64
#define CGRID 1024             // k_class_p grid

#define NB    100              // binning blocks
#define CHB   500              // elements per binning block (NB*CHB == TT)
#define PL    8                // elements per lane (64*8 >= CHB)
#define PREPB 268              // weight-packing blocks in k_prep
#define MBB   6250             // mem bit-pack blocks (1.6M bytes / 256)
#define ECVB  12500            // emb->bf16 conversion blocks (3.2M chunks/256)

// ws layout (bytes)
#define WS_OFFS   0
#define WS_CNT    64                        // NB*LL ints = 3200
#define WS_BASE   4096                      // NB*LL ints
#define WS_BINS   8192                      // PADT*4 = 202240
#define WS_WCP    210432                    // 48 KB, 16B aligned
#define WS_WRP    (WS_WCP + 6*8*64*16)      // 259584; 1 MB
#define WS_MB     (WS_WRP + 8*8*16*64*16)   // 1308160; 1.6 MB bit-packed mem
#define WS_E16    (WS_MB + NROWS*8)         // 2908160; 51.2 MB
#define WS_NEED   (WS_E16 + (size_t)NROWS*DD*2)

typedef unsigned short u16;
typedef unsigned int   u32;
typedef unsigned long long u64;
typedef unsigned char  u8;
typedef __attribute__((ext_vector_type(8))) short bf16x8;
typedef __attribute__((ext_vector_type(4))) float f32x4;
typedef __attribute__((ext_vector_type(4))) unsigned int u32x4;

#define SWZ(row, byte) ((byte) ^ (((row)&7)<<4))

__device__ __forceinline__ u32 bfbits(float f){
  __hip_bfloat16 h = __float2bfloat16(f);
  return (u32)*reinterpret_cast<unsigned short*>(&h);
}
__device__ __forceinline__ u32 pk(float lo, float hi){
  return bfbits(lo) | (bfbits(hi) << 16);
}
__device__ __forceinline__ float qreduce16(float ss){
  ss += __shfl_xor(ss, 1, 64);
  ss += __shfl_xor(ss, 2, 64);
  ss += __shfl_xor(ss, 4, 64);
  ss += __shfl_xor(ss, 8, 64);
  return ss;
}
__device__ __forceinline__ float fast_tanh(float x){
  float a = fabsf(x);
  float e = __expf(-2.0f*a);
  float t = (1.0f - e) * __builtin_amdgcn_rcpf(1.0f + e);
  return copysignf(t, x);
}
__device__ __forceinline__ float rnorm_scale(float ss){
  return __builtin_amdgcn_rcpf(fmaxf(__builtin_amdgcn_sqrtf(ss), 1e-12f));
}
__device__ __forceinline__ void nt_store_v4(void* p, u32x4 v){
  __builtin_nontemporal_store(v, (u32x4*)p);
}
// async global -> LDS, 16B per lane. LDS dest is wave-uniform base + lane*16.
__device__ __forceinline__ void gload16(const void* g, void* l){
  __builtin_amdgcn_global_load_lds(
      (const __attribute__((address_space(1))) void*)g,
      (__attribute__((address_space(3))) void*)l, 16, 0, 0);
}

// --- prep: Wc/Wr frag-pack; bin counts; mem bit-pack; emb->bf16 -------------
__global__ __launch_bounds__(256) void k_prep(
    const float* __restrict__ Wc, const float* __restrict__ Wr,
    uint4* __restrict__ wcp, uint4* __restrict__ wrp,
    const int* __restrict__ layer, int* __restrict__ cnt,
    const int* __restrict__ mem, u8* __restrict__ mb8,
    const float* __restrict__ emb, u16* __restrict__ e16)
{
  if (blockIdx.x >= PREPB + NB + MBB){
    // emb f32 -> e16 bf16 (8 elems/thread)
    size_t gid = (size_t)(blockIdx.x - PREPB - NB - MBB)*256 + threadIdx.x;
    const float4* s4 = (const float4*)(emb + gid*8);
    float4 a = s4[0], b = s4[1];
    u32x4 o;
    o.x = pk(a.x,a.y); o.y = pk(a.z,a.w); o.z = pk(b.x,b.y); o.w = pk(b.z,b.w);
    nt_store_v4(e16 + gid*8, o);
    return;
  }
  if (blockIdx.x >= PREPB + NB){
    int gid = (blockIdx.x - PREPB - NB)*256 + threadIdx.x;
    const int4* s4 = (const int4*)(mem + (size_t)gid*8);
    int4 a = s4[0], b = s4[1];
    u8 byte = (u8)((a.x!=0) | ((a.y!=0)<<1) | ((a.z!=0)<<2) | ((a.w!=0)<<3)
             | ((b.x!=0)<<4) | ((b.y!=0)<<5) | ((b.z!=0)<<6) | ((b.w!=0)<<7));
    __builtin_nontemporal_store(byte, &mb8[gid]);
    return;
  }
  if (blockIdx.x >= PREPB){
    const int bb = blockIdx.x - PREPB, lane = threadIdx.x;
    if (lane >= 64) return;
    const int lim = bb*CHB + CHB;
    int i0 = bb*CHB + lane*PL, i1 = i0 + PL; if (i1 > lim) i1 = lim;
    int c[LL] = {0,0,0,0,0,0,0,0};
    for (int i = i0; i < i1; ++i){
      int l = layer[i];
      #pragma unroll
      for (int k = 0; k < LL; ++k) c[k] += (l == k);
    }
    #pragma unroll
    for (int k = 0; k < LL; ++k){
      int v = c[k];
      v += __shfl_xor(v, 1, 64); v += __shfl_xor(v, 2, 64);
      v += __shfl_xor(v, 4, 64); v += __shfl_xor(v, 8, 64);
      v += __shfl_xor(v, 16, 64); v += __shfl_xor(v, 32, 64);
      if (lane == k) cnt[bb*LL + k] = v;
    }
    return;
  }
  int id = blockIdx.x*blockDim.x + threadIdx.x;
  if (id < 3072){                       // wcp: kt 0..5, nt 0..7
    int lane = id & 63, nt = (id >> 6) & 7, kt = id >> 9;
    int k0 = kt*32 + (lane>>4)*8, n = nt*16 + (lane&15);
    u32 p[4];
    #pragma unroll
    for (int e2 = 0; e2 < 4; ++e2)
      p[e2] = pk(Wc[(k0 + 2*e2)*DD + n], Wc[(k0 + 2*e2 + 1)*DD + n]);
    wcp[id] = make_uint4(p[0], p[1], p[2], p[3]);
  } else if (id < 3072 + 65536){        // wrp: l, kt 0..7, nt 0..15
    int id2 = id - 3072;
    int lane = id2 & 63, nt = (id2>>6) & 15, kt = (id2>>10) & 7, l = id2 >> 13;
    int k0 = kt*32 + (lane>>4)*8, n = nt*16 + (lane&15);
    const float* w = Wr + (size_t)l*65536;
    u32 p[4];
    #pragma unroll
    for (int e2 = 0; e2 < 4; ++e2)
      p[e2] = pk(w[(k0 + 2*e2)*256 + n], w[(k0 + 2*e2 + 1)*256 + n]);
    wrp[id2] = make_uint4(p[0], p[1], p[2], p[3]);
  }
}

// --- bin2: offsets + per-block bases + pad fill (1 tiny block) ---------------
__global__ __launch_bounds__(64) void k_bin2(const int* __restrict__ cnt,
                                             int* __restrict__ offs,
                                             int* __restrict__ gbase,
                                             int* __restrict__ bins)
{
  __shared__ int pre[NB][LL];
  __shared__ int tot[LL], soffs[LL+1];
  const int t = threadIdx.x;
  if (t < LL){
    int acc = 0;
    for (int bb = 0; bb < NB; ++bb){ pre[bb][t] = acc; acc += cnt[bb*LL + t]; }
    tot[t] = acc;
  }
  __syncthreads();
  if (t == 0){
    int acc = 0;
    for (int l = 0; l < LL; ++l){
      soffs[l] = acc; offs[l] = acc;
      acc += ((tot[l] + BT - 1)/BT)*BT;
    }
    soffs[LL] = acc; offs[LL] = acc;
  }
  __syncthreads();
  for (int idx = t; idx < NB*LL; idx += 64){
    int bb = idx >> 3, k = idx & 7;
    gbase[idx] = soffs[k] + pre[bb][k];
  }
  const int k = t >> 3, sub = t & 7;
  const int sz = soffs[k+1] - soffs[k];
  for (int i = tot[k] + sub; i < sz; i += 8) bins[soffs[k] + i] = -1;
}

// --- bin3: ordered scatter (NB one-wave blocks) -------------------------------
__global__ __launch_bounds__(64) void k_bin3(const int* __restrict__ layer,
                                             const int* __restrict__ gbase,
                                             int* __restrict__ bins)
{
  const int bb = blockIdx.x, lane = threadIdx.x;
  const int lim = bb*CHB + CHB;
  int i0 = bb*CHB + lane*PL, i1 = i0 + PL; if (i1 > lim) i1 = lim;
  int c[LL] = {0,0,0,0,0,0,0,0};
  for (int i = i0; i < i1; ++i){
    int l = layer[i];
    #pragma unroll
    for (int k = 0; k < LL; ++k) c[k] += (l == k);
  }
  int start[LL];
  #pragma unroll
  for (int k = 0; k < LL; ++k){
    int v = c[k];
    #pragma unroll
    for (int d = 1; d < 64; d <<= 1){
      int u = __shfl_up(v, d, 64);
      if (lane >= d) v += u;
    }
    start[k] = gbase[bb*LL + k] + v - c[k];
  }
  for (int i = i0; i < i1; ++i){
    int l = layer[i];
    #pragma unroll
    for (int k = 0; k < LL; ++k)
      if (l == k) bins[start[k]++] = i;
  }
}

// --- class update (pipelined): dst = l2norm(tanh([e16;mem] @ Wc + bc)) -------
// 256 thr, grid CGRID, tiles strided by CGRID. Double-buffered gload_lds
// staging (16KB/tile in flight, zero VGPR payload). Pre-swizzled global src,
// linear LDS dest, XOR-swizzled reads (2-way banks = free). Wave w owns nt
// tiles {2w,2w+1}; Wc frags in regs; mem unpacked from mbits via ds_write.
template<bool W16, bool WF32>
__global__ __launch_bounds__(256) void k_class_p(
    const u16* __restrict__ src16, u16* __restrict__ e16out,
    float* __restrict__ dstf, const u64* __restrict__ mbits,
    const uint4* __restrict__ wcp, const float* __restrict__ bc)
{
  __shared__ __align__(16) u16 sE[2][8192];   // 2 x 16 KB, rows 256B
  __shared__ __align__(16) u16 sM[2][4096];   // 2 x  8 KB, rows 128B
  __shared__ float sPart[64][4];

  const int tid = threadIdx.x;
  const int lane = tid & 63, wid = tid >> 6;
  const int colj = lane & 15, qw = lane >> 4;
  const int mrow = tid >> 2, mq = tid & 3;

  // Wc B-frags (L2-hot) -> registers
  bf16x8 wf[6][2];
  #pragma unroll
  for (int kt = 0; kt < 6; ++kt)
    #pragma unroll
    for (int j = 0; j < 2; ++j)
      wf[kt][j] = *(const bf16x8*)&wcp[(kt*8 + 2*wid + j)*64 + lane];
  const float b0 = bc[(2*wid)*16 + colj];
  const float b1 = bc[(2*wid+1)*16 + colj];

  // issue 4 x 1KB gload_lds for a tile into sE[buf] (this wave's 4KB span)
  auto issue = [&](int buf, int tile){
    #pragma unroll
    for (int i = 0; i < 4; ++i){
      int p   = wid*4096 + i*1024 + lane*16;       // LDS byte pos
      int row = p >> 8;
      int cG  = ((p >> 4) & 15) ^ (row & 7);       // pre-swizzled source chunk
      const u16* g = src16 + (((size_t)tile*64 + row) << 7) + cG*8;
      gload16(g, (void*)&sE[buf][(wid*4096 + i*1024) >> 1]);
    }
  };

  int t = blockIdx.x;
  int cur = 0;
  issue(0, t);
  u64 mv = mbits[(size_t)t*64 + mrow];

  for (;;){
    // ---- unpack mem bits -> sM[cur] (swizzled) ----
    {
      u32 s = (u32)(mv >> (mq*16)) & 0xFFFFu;
      u32 p[8];
      #pragma unroll
      for (int jj = 0; jj < 8; ++jj){
        u32 lo = (s >> (2*jj))     & 1u;
        u32 hi = (s >> (2*jj + 1)) & 1u;
        p[jj] = (lo ? 0x3F80u : 0u) | (hi ? 0x3F800000u : 0u);
      }
      int c0 = (mq*2)     ^ (mrow & 7);
      int c1 = (mq*2 + 1) ^ (mrow & 7);
      *(uint4*)&sM[cur][mrow*64 + c0*8] = make_uint4(p[0],p[1],p[2],p[3]);
      *(uint4*)&sM[cur][mrow*64 + c1*8] = make_uint4(p[4],p[5],p[6],p[7]);
    }
    __syncthreads();                     // bar1: tile t fully staged

    const int tn = t + CGRID;
    const bool more = (tn < NPASS);
    if (more){
      issue(cur ^ 1, tn);                // prefetch rides under MFMA
      mv = mbits[(size_t)tn*64 + mrow];
    }

    // ---- MFMA ----
    f32x4 acc[4][2];
    #pragma unroll
    for (int m = 0; m < 4; ++m){
      acc[m][0] = (f32x4){0.f,0.f,0.f,0.f};
      acc[m][1] = (f32x4){0.f,0.f,0.f,0.f};
    }
    #pragma unroll
    for (int m = 0; m < 4; ++m){
      const int row = m*16 + colj;
      #pragma unroll
      for (int kt = 0; kt < 4; ++kt){
        bf16x8 afr = *(bf16x8*)&sE[cur][row*128 + (((kt*4+qw) ^ (row&7))*8)];
        acc[m][0] = __builtin_amdgcn_mfma_f32_16x16x32_bf16(afr, wf[kt][0], acc[m][0], 0,0,0);
        acc[m][1] = __builtin_amdgcn_mfma_f32_16x16x32_bf16(afr, wf[kt][1], acc[m][1], 0,0,0);
      }
      #pragma unroll
      for (int kt = 4; kt < 6; ++kt){
        bf16x8 afr = *(bf16x8*)&sM[cur][row*64 + ((((kt-4)*4+qw) ^ (row&7))*8)];
        acc[m][0] = __builtin_amdgcn_mfma_f32_16x16x32_bf16(afr, wf[kt][0], acc[m][0], 0,0,0);
        acc[m][1] = __builtin_amdgcn_mfma_f32_16x16x32_bf16(afr, wf[kt][1], acc[m][1], 0,0,0);
      }
    }
    // ---- tanh + cross-wave l2norm partials ----
    #pragma unroll
    for (int m = 0; m < 4; ++m){
      #pragma unroll
      for (int r = 0; r < 4; ++r){
        float t0 = fast_tanh(acc[m][0][r] + b0);
        float t1 = fast_tanh(acc[m][1][r] + b1);
        acc[m][0][r] = t0; acc[m][1][r] = t1;
        float ss = qreduce16(t0*t0 + t1*t1);
        if (colj == 0) sPart[m*16 + qw*4 + r][wid] = ss;
      }
    }
    __syncthreads();                     // bar2: sPart ready; reads of buf done

    const size_t rowbase = (size_t)t*64;
    if constexpr (W16){
      // scale -> linear bf16 image in sE[cur] -> flat 16B nt stores
      u16* so = sE[cur];
      #pragma unroll
      for (int m = 0; m < 4; ++m){
        #pragma unroll
        for (int r = 0; r < 4; ++r){
          int row = m*16 + qw*4 + r;
          f32x4 p = *(f32x4*)sPart[row];
          float sc = rnorm_scale(p[0] + p[1] + p[2] + p[3]);
          so[row*128 + (2*wid)*16 + colj]      = (u16)bfbits(acc[m][0][r]*sc);
          so[row*128 + (2*wid+1)*16 + colj]    = (u16)bfbits(acc[m][1][r]*sc);
        }
      }
      __syncthreads();                   // bar3: out image complete
      #pragma unroll
      for (int k = 0; k < 4; ++k){
        int c = tid + k*256;
        nt_store_v4((void*)(e16out + rowbase*DD + c*8), *(const u32x4*)&so[c*8]);
      }
    }
    if constexpr (WF32){
      #pragma unroll
      for (int m = 0; m < 4; ++m){
        #pragma unroll
        for (int r = 0; r < 4; ++r){
          int row = m*16 + qw*4 + r;
          f32x4 p = *(f32x4*)sPart[row];
          float sc = rnorm_scale(p[0] + p[1] + p[2] + p[3]);
          dstf[(rowbase+row)*DD + (2*wid)*16 + colj]   = acc[m][0][r]*sc;
          dstf[(rowbase+row)*DD + (2*wid+1)*16 + colj] = acc[m][1][r]*sc;
        }
      }
    }
    if (!more) break;
    t = tn; cur ^= 1;
  }
}

// --- fallback class (R13): f32 src, direct stores ----------------------------
template<bool S16, bool W16, bool WF32>
__global__ __launch_bounds__(512) void k_class_fb(
    const float* __restrict__ srcf, const u16* __restrict__ src16,
    u16* __restrict__ e16, float* __restrict__ dstf,
    const u64* __restrict__ mbits,
    const uint4* __restrict__ wcp, const float* __restrict__ bc)
{
  __shared__ __align__(16) char smem[24576];
  __shared__ float sPart[64][9];
  __shared__ float sScale[64];
  u16* sA = (u16*)smem;

  const int tid = threadIdx.x;
  const int lane = tid & 63, wid = tid >> 6;
  const int colj = lane & 15, qw = lane >> 4;
  const int rowbase = blockIdx.x * 64;

  int crow[2], ccc[2];
  uint4  eA[2];
  float4 fA[2][2];
  #pragma unroll
  for (int v = 0; v < 2; ++v){
    int c = tid + v*512;
    crow[v] = c >> 4; ccc[v] = c & 15;
    if constexpr (S16){
      eA[v] = *(const uint4*)(src16 + (size_t)(rowbase+crow[v])*DD + ccc[v]*8);
    } else {
      const float4* s4 = (const float4*)(srcf + (size_t)(rowbase+crow[v])*DD + ccc[v]*8);
      fA[v][0] = s4[0]; fA[v][1] = s4[1];
    }
  }
  u64 mv = 0;
  if (tid < 256) mv = mbits[rowbase + (tid >> 2)];

  bf16x8 wf[6];
  #pragma unroll
  for (int kt = 0; kt < 6; ++kt)
    wf[kt] = *(const bf16x8*)&wcp[(kt*8 + wid)*64 + lane];
  const float b = bc[wid*16 + colj];

  #pragma unroll
  for (int v = 0; v < 2; ++v){
    uint4 out;
    if constexpr (S16){
      out = eA[v];
    } else {
      float4 a = fA[v][0], bb2 = fA[v][1];
      out = make_uint4(pk(a.x,a.y), pk(a.z,a.w), pk(bb2.x,bb2.y), pk(bb2.z,bb2.w));
    }
    *(uint4*)((char*)sA + crow[v]*384 + SWZ(crow[v], ccc[v]*16)) = out;
  }
  if (tid < 256){
    const int r = tid >> 2, q = tid & 3;
    u32 s = (u32)(mv >> (q*16)) & 0xFFFFu;
    u32 p[8];
    #pragma unroll
    for (int jj = 0; jj < 8; ++jj){
      u32 lo = (s >> (2*jj))     & 1u;
      u32 hi = (s >> (2*jj + 1)) & 1u;
      p[jj] = (lo ? 0x3F80u : 0u) | (hi ? 0x3F800000u : 0u);
    }
    *(uint4*)((char*)sA + r*384 + SWZ(r, 256 + q*32))      = make_uint4(p[0],p[1],p[2],p[3]);
    *(uint4*)((char*)sA + r*384 + SWZ(r, 256 + q*32 + 16)) = make_uint4(p[4],p[5],p[6],p[7]);
  }
  __syncthreads();

  f32x4 acc[4];
  #pragma unroll
  for (int m = 0; m < 4; ++m) acc[m] = (f32x4){0.f,0.f,0.f,0.f};
  #pragma unroll
  for (int m = 0; m < 4; ++m){
    int row = m*16 + colj;
    #pragma unroll
    for (int kt = 0; kt < 6; ++kt){
      bf16x8 afr = *(bf16x8*)((char*)sA + row*384 + SWZ(row, kt*64 + qw*16));
      acc[m] = __builtin_amdgcn_mfma_f32_16x16x32_bf16(afr, wf[kt], acc[m], 0,0,0);
    }
  }
  #pragma unroll
  for (int m = 0; m < 4; ++m){
    #pragma unroll
    for (int r = 0; r < 4; ++r){
      float t = fast_tanh(acc[m][r] + b);
      acc[m][r] = t;
      float ss = qreduce16(t*t);
      if (colj == 0) sPart[m*16 + qw*4 + r][wid] = ss;
    }
  }
  __syncthreads();
  if (tid < 64){
    float s = 0.f;
    #pragma unroll
    for (int i = 0; i < 8; ++i) s += sPart[tid][i];
    sScale[tid] = rnorm_scale(s);
  }
  __syncthreads();

  if constexpr (W16){
    u16* so = (u16*)smem;
    #pragma unroll
    for (int m = 0; m < 4; ++m){
      #pragma unroll
      for (int r = 0; r < 4; ++r){
        int row = m*16 + qw*4 + r;
        so[row*128 + wid*16 + colj] = (u16)bfbits(acc[m][r]*sScale[row]);
      }
    }
    __syncthreads();
    const u32x4* sp = (const u32x4*)smem;
    u32x4* gp = (u32x4*)(e16 + (size_t)rowbase*DD);
    nt_store_v4(gp + tid,       sp[tid]);
    nt_store_v4(gp + tid + 512, sp[tid + 512]);
  }
  if constexpr (WF32){
    #pragma unroll
    for (int m = 0; m < 4; ++m){
      #pragma unroll
      for (int r = 0; r < 4; ++r){
        int row = m*16 + qw*4 + r;
        dstf[(size_t)(rowbase+row)*DD + wid*16 + colj] = acc[m][r]*sScale[row];
      }
    }
  }
}

// --- relation update: 64 same-layer triples/block (R13, unchanged) -----------
template<bool S16, bool W16, bool WF32>
__global__ __launch_bounds__(256) void k_rel(
    const float* __restrict__ ef32, u16* __restrict__ e16,
    float* __restrict__ dstf,
    const int* __restrict__ subj, const int* __restrict__ obj,
    const uint4* __restrict__ wrp, const float* __restrict__ br,
    const int* __restrict__ offs, const int* __restrict__ bins)
{
  __shared__ __align__(16) char smem[32768];
  __shared__ float sBr[256];
  __shared__ float sPart[BT][4];
  __shared__ int   sS[BT], sO[BT];
  u16* sA = (u16*)smem;

  const int tid  = threadIdx.x;
  const int base = blockIdx.x * BT;
  if (base >= offs[LL]) return;
  int l = 0;
  while (l < LL-1 && base >= offs[l+1]) ++l;

  const int lane = tid & 63, wid = tid >> 6;
  const int colj = lane & 15, qw = lane >> 4;

  const uint4* wb = wrp + (size_t)l*8192 + lane;
  bf16x8 wf[8][4];
  #pragma unroll
  for (int n = 0; n < 4; ++n){
    wf[0][n] = *(const bf16x8*)&wb[(0*16 + wid*4 + n)*64];
    wf[1][n] = *(const bf16x8*)&wb[(1*16 + wid*4 + n)*64];
  }

  sBr[tid] = br[l*256 + tid];

  const int ti = tid >> 2, q = tid & 3;
  int id = bins[base + ti];
  int rs = -1, ro = -1;
  if (id >= 0){ rs = subj[id]; ro = obj[id]; }
  if (q == 0){ sS[ti] = rs; sO[ti] = ro; }
  const int rr = (q < 2) ? rs : ro;
  if constexpr (S16){
    const u16* srcp = e16 + (size_t)rr*DD + (q & 1)*64;
    #pragma unroll
    for (int j = 0; j < 8; ++j){
      uint4 w = (id >= 0) ? ((const uint4*)srcp)[j] : make_uint4(0u,0u,0u,0u);
      *(uint4*)((char*)sA + ti*512 + SWZ(ti, q*128 + j*16)) = w;
    }
  } else {
    const float* srcp = ef32 + (size_t)rr*DD + (q & 1)*64;
    #pragma unroll
    for (int j = 0; j < 8; ++j){
      uint4 w;
      if (id >= 0){
        float4 a = ((const float4*)srcp)[2*j], b = ((const float4*)srcp)[2*j+1];
        w = make_uint4(pk(a.x,a.y), pk(a.z,a.w), pk(b.x,b.y), pk(b.z,b.w));
      } else w = make_uint4(0u,0u,0u,0u);
      *(uint4*)((char*)sA + ti*512 + SWZ(ti, q*128 + j*16)) = w;
    }
  }
  __syncthreads();

  f32x4 acc[4][4];
  #pragma unroll
  for (int m = 0; m < 4; ++m)
    #pragma unroll
    for (int n = 0; n < 4; ++n) acc[m][n] = (f32x4){0.f,0.f,0.f,0.f};

  #pragma unroll
  for (int kt = 0; kt < 8; ++kt){
    if (kt + 2 < 8){
      #pragma unroll
      for (int n = 0; n < 4; ++n)
        wf[kt+2][n] = *(const bf16x8*)&wb[((kt+2)*16 + wid*4 + n)*64];
    }
    #pragma unroll
    for (int m = 0; m < 4; ++m){
      int row = m*16 + colj;
      bf16x8 afr = *(bf16x8*)((char*)sA + row*512 + SWZ(row, kt*64 + qw*16));
      #pragma unroll
      for (int n = 0; n < 4; ++n)
        acc[m][n] = __builtin_amdgcn_mfma_f32_16x16x32_bf16(afr, wf[kt][n], acc[m][n], 0,0,0);
    }
  }

  #pragma unroll
  for (int m = 0; m < 4; ++m){
    #pragma unroll
    for (int n = 0; n < 4; ++n){
      float b = sBr[(wid*4 + n)*16 + colj];
      #pragma unroll
      for (int r = 0; r < 4; ++r)
        acc[m][n][r] = fast_tanh(acc[m][n][r] + b);
    }
    #pragma unroll
    for (int r = 0; r < 4; ++r){
      float ss = acc[m][0][r]*acc[m][0][r] + acc[m][1][r]*acc[m][1][r]
               + acc[m][2][r]*acc[m][2][r] + acc[m][3][r]*acc[m][3][r];
      ss = qreduce16(ss);
      if (colj == 0) sPart[m*16 + qw*4 + r][wid] = ss;
    }
  }
  __syncthreads();

  const int h = wid >> 1;
  if constexpr (W16){
    #pragma unroll
    for (int m = 0; m < 4; ++m){
      #pragma unroll
      for (int r = 0; r < 4; ++r){
        int tri = m*16 + qw*4 + r;
        float ss = sPart[tri][2*h] + sPart[tri][2*h + 1];
        float sc = rnorm_scale(ss);
        #pragma unroll
        for (int n = 0; n < 4; ++n){
          int col = (wid*4 + n)*16 + colj;
          float v = acc[m][n][r]*sc;
          *(u16*)((char*)smem + tri*512 + ((col*2) ^ ((tri&7)<<4))) = (u16)bfbits(v);
        }
      }
    }
    __syncthreads();
    #pragma unroll
    for (int k = 0; k < 8; ++k){
      int c = tid + k*256;
      int tri = c >> 5, hh = (c >> 4) & 1, sub = c & 15;
      int row = hh ? sO[tri] : sS[tri];
      if (row >= 0){
        u32x4 v = *(const u32x4*)((char*)smem + ((c*16) ^ ((tri&7)<<4)));
        nt_store_v4((u32x4*)(e16 + (size_t)row*DD) + sub, v);
      }
    }
  }
  if constexpr (WF32){
    #pragma unroll
    for (int m = 0; m < 4; ++m){
      #pragma unroll
      for (int r = 0; r < 4; ++r){
        int tri = m*16 + qw*4 + r;
        int row = h ? sO[tri] : sS[tri];
        if (row < 0) continue;
        float ss = sPart[tri][2*h] + sPart[tri][2*h + 1];
        float sc = rnorm_scale(ss);
        #pragma unroll
        for (int n = 0; n < 4; ++n){
          int cc = (wid*4 + n)*16 + colj - h*DD;
          dstf[(size_t)row*DD + cc] = acc[m][n][r]*sc;
        }
      }
    }
  }
}

extern "C" void kernel_launch(void* const* d_in, const int* in_sizes, int n_in,
                              void* d_out, int out_size, void* d_ws, size_t ws_size,
                              hipStream_t stream) {
  (void)in_sizes; (void)n_in; (void)out_size;
  const float* emb  = (const float*)d_in[0];
  const int*   mem  = (const int*)  d_in[1];
  const int*   subj = (const int*)  d_in[2];
  const int*   obj  = (const int*)  d_in[3];
  const int*   lay  = (const int*)  d_in[4];
  const float* Wc   = (const float*)d_in[5];
  const float* bc   = (const float*)d_in[6];
  const float* Wr   = (const float*)d_in[7];
  const float* br   = (const float*)d_in[8];

  float* e   = (float*)d_out;
  char*  wsb = (char*)d_ws;
  int*   offs  = (int*)(wsb + WS_OFFS);
  int*   cnt   = (int*)(wsb + WS_CNT);
  int*   gbase = (int*)(wsb + WS_BASE);
  int*   bins  = (int*)(wsb + WS_BINS);
  uint4* wcp   = (uint4*)(wsb + WS_WCP);
  uint4* wrp   = (uint4*)(wsb + WS_WRP);
  u64*   mbits = (u64*)(wsb + WS_MB);
  u8*    mb8   = (u8*)(wsb + WS_MB);
  u16*   e16   = (u16*)(wsb + WS_E16);

  const bool full = (ws_size >= WS_NEED);
  const int prep_grid = PREPB + NB + MBB + (full ? ECVB : 0);
  k_prep<<<prep_grid, 256, 0, stream>>>(Wc, Wr, wcp, wrp, lay, cnt, mem, mb8, emb, e16);
  k_bin2<<<1, 64, 0, stream>>>(cnt, offs, gbase, bins);
  k_bin3<<<NB, 64, 0, stream>>>(lay, gbase, bins);

  if (full){
    // bf16-resident e path, gload_lds-pipelined class
    k_class_p<true,false><<<CGRID, 256, 0, stream>>>(
        e16, e16, nullptr, mbits, wcp, bc);
    k_rel<true,true,false><<<PADT/BT, 256, 0, stream>>>(
        nullptr, e16, nullptr, subj, obj, wrp, br, offs, bins);
    k_class_p<false,true><<<CGRID, 256, 0, stream>>>(
        e16, nullptr, e, mbits, wcp, bc);
    k_rel<false,false,true><<<PADT/BT, 256, 0, stream>>>(
        e, nullptr, e, subj, obj, wrp, br, offs, bins);
  } else {
    // f32 fallback (e lives in d_out; mbits region is tiny and always fits)
    k_class_fb<false,false,true><<<NPASS, 512, 0, stream>>>(
        emb, nullptr, nullptr, e, mbits, wcp, bc);
    k_rel<false,false,true><<<PADT/BT, 256, 0, stream>>>(
        e, nullptr, e, subj, obj, wrp, br, offs, bins);
    k_class_fb<false,false,true><<<NPASS, 512, 0, stream>>>(
        e, nullptr, nullptr, e, mbits, wcp, bc);
    k_rel<false,false,true><<<PADT/BT, 256, 0, stream>>>(
        e, nullptr, e, subj, obj, wrp, br, offs, bins);
  }
}